// Round 9
// baseline (2814591.211 us; speedup 1.0000x reference)
//
#include <hip/hip_runtime.h>

// SimpleRNN: 2-layer ReLU RNN, B=64 T=512 I=256 H=1024 O=1000, fp32 in/out.
// Round 9: r8's XCD-local persistent scan + CU-L1 staleness fixes:
//  (1) buffer_inv sc0 (vector-L1 invalidate) in every poll iteration + before
//      data ladders  (2) sc0 on h/flag stores (write-through CU caches to the
//      XCD L2)  (3) h rings deepened 4 -> 16 (no L1-lifetime address reuse).
// 512 blocks x 64 thr x 64KB LDS = exactly 2/CU -> 64 blocks per XCD; roles
// claimed via XCC_ID + per-XCD atomic rank. All h/flag traffic intra-XCD.

typedef float f32x4 __attribute__((ext_vector_type(4)));
typedef short bf16x8 __attribute__((ext_vector_type(8)));
typedef unsigned short u16;
typedef unsigned int u32;
typedef u32 u32x4 __attribute__((ext_vector_type(4)));

#define MFMA_BF16(a, b, c) __builtin_amdgcn_mfma_f32_16x16x32_bf16((a), (b), (c), 0, 0, 0)

#define GLDS16(g, l) __builtin_amdgcn_global_load_lds( \
    (const __attribute__((address_space(1))) unsigned int*)(g), \
    (__attribute__((address_space(3))) unsigned int*)(l), 16, 0, 0)

// two XCD-local loads (CU-cache-coherent, served by the XCD's L2)
#define LD2L2(d0, d1, b_, O1, O2) asm volatile( \
    "global_load_dwordx4 %0, %2, off offset:" O1 " sc0\n\t" \
    "global_load_dwordx4 %1, %2, off offset:" O2 " sc0" \
    : "=&v"(d0), "=&v"(d1) : "v"(b_))
// one normal cached 16B load + literal offset (read-only weights/pre)
#define LD1CA(d, b_, O) asm volatile( \
    "global_load_dwordx4 %0, %1, off offset:" O : "=&v"(d) : "v"(b_))
// XCD-local store (write-through CU caches into the local L2)
#define STORE_L2(p, v) asm volatile("global_store_dword %0, %1, off sc0" :: "v"(p), "v"(v) : "memory")
// literal-counted vmcnt wait, pinned against scheduler motion
#define WAITVM(n) do { __builtin_amdgcn_sched_barrier(0); \
    asm volatile("s_waitcnt vmcnt(" #n ")" ::: "memory"); \
    __builtin_amdgcn_sched_barrier(0); } while (0)

__device__ __forceinline__ u16 f2b(float f) {  // RNE f32 -> bf16 bits
  unsigned int u = __builtin_bit_cast(unsigned int, f);
  u = (u + 0x7fffu + ((u >> 16) & 1u)) >> 16;
  return (u16)u;
}
__device__ __forceinline__ float b2f(u16 b) {
  unsigned int u = ((unsigned int)b) << 16;
  return __builtin_bit_cast(float, u);
}

// packed u32 = hi-bf16 (low16) | lo-bf16 (high16); extract 8-elem bf16 frags
__device__ __forceinline__ bf16x8 hi_frag(u32x4 d0, u32x4 d1) {
  u32x4 r;
  r[0] = __builtin_amdgcn_perm(d0[1], d0[0], 0x05040100u);
  r[1] = __builtin_amdgcn_perm(d0[3], d0[2], 0x05040100u);
  r[2] = __builtin_amdgcn_perm(d1[1], d1[0], 0x05040100u);
  r[3] = __builtin_amdgcn_perm(d1[3], d1[2], 0x05040100u);
  return __builtin_bit_cast(bf16x8, r);
}
__device__ __forceinline__ bf16x8 lo_frag(u32x4 d0, u32x4 d1) {
  u32x4 r;
  r[0] = __builtin_amdgcn_perm(d0[1], d0[0], 0x07060302u);
  r[1] = __builtin_amdgcn_perm(d0[3], d0[2], 0x07060302u);
  r[2] = __builtin_amdgcn_perm(d1[1], d1[0], 0x07060302u);
  r[3] = __builtin_amdgcn_perm(d1[3], d1[2], 0x07060302u);
  return __builtin_bit_cast(bf16x8, r);
}

// ---------------- elementwise helpers ----------------
__global__ void cast_kernel(const float* __restrict__ s, u16* __restrict__ d, int n4) {
  int i = blockIdx.x * blockDim.x + threadIdx.x;
  if (i >= n4) return;
  float4 v = ((const float4*)s)[i];
  ushort4 o;
  o.x = f2b(v.x); o.y = f2b(v.y); o.z = f2b(v.z); o.w = f2b(v.w);
  ((ushort4*)d)[i] = o;
}

__global__ void bias_kernel(const float* __restrict__ a, const float* __restrict__ b,
                            float* __restrict__ o, int n) {
  int i = blockIdx.x * blockDim.x + threadIdx.x;
  if (i < n) o[i] = a[i] + b[i];
}

// zero ring slot 15 (h(-1)=0), flags, rank counters; plain stores are made
// globally visible by the dispatch-boundary release/acquire (r7-proven).
__global__ void init_sync_kernel(u32* __restrict__ h0ring, u32* __restrict__ h1ring,
                                 u32* __restrict__ flags, int* __restrict__ cnt) {
  int i = blockIdx.x * blockDim.x + threadIdx.x;  // 0..65535
  int g = i >> 13, off = i & 8191;
  h0ring[g * 131072 + 15 * 8192 + off] = 0;
  h1ring[g * 131072 + 15 * 8192 + off] = 0;
  if (i < 512) flags[i] = 0;
  if (i < 8) cnt[i] = 0;
}

// ---------------- input GEMM: pre = A @ Bw^T  (A:[M][K], Bw:[1024][K]) ----------------
// rows m=b*512+t -> out row t*64+b (time-major). Out: bf16 [32768][1024].
__global__ __launch_bounds__(256) void gemm_pre(const u16* __restrict__ A,
                                                const u16* __restrict__ Bw,
                                                u16* __restrict__ outp, int K) {
  __shared__ u16 As[128 * 32];
  __shared__ u16 Bs[128 * 32];
  const int tid = threadIdx.x;
  const int lane = tid & 63;
  const int w = tid >> 6;
  const int nt = blockIdx.x & 7;
  const int mt = blockIdx.x >> 3;
  const int m_base = mt * 128;
  const int n_base = nt * 128;

  const int srow = w * 32 + (lane >> 2);
  const int schunk = (lane & 3) ^ (srow & 3);
  const u16* Ag0 = A + (size_t)(m_base + srow) * K + schunk * 8;
  const u16* Ag1 = A + (size_t)(m_base + srow + 16) * K + schunk * 8;
  const u16* Bg0 = Bw + (size_t)(n_base + srow) * K + schunk * 8;
  const u16* Bg1 = Bw + (size_t)(n_base + srow + 16) * K + schunk * 8;
  u16* AsD0 = As + (w * 32) * 32;
  u16* AsD1 = As + (w * 32 + 16) * 32;
  u16* BsD0 = Bs + (w * 32) * 32;
  u16* BsD1 = Bs + (w * 32 + 16) * 32;

  const int wm = (w & 1) * 64;
  const int wn = (w >> 1) * 64;
  const int rl = lane & 15;
  const int q = lane >> 4;

  f32x4 acc[4][4] = {};

  for (int k0 = 0; k0 < K; k0 += 32) {
    __syncthreads();
    GLDS16(Ag0 + k0, AsD0);
    GLDS16(Ag1 + k0, AsD1);
    GLDS16(Bg0 + k0, BsD0);
    GLDS16(Bg1 + k0, BsD1);
    __syncthreads();
    bf16x8 af[4], bfv[4];
#pragma unroll
    for (int i = 0; i < 4; ++i) {
      int ra = wm + i * 16 + rl;
      af[i] = *(const bf16x8*)(As + ra * 32 + ((q ^ (ra & 3)) << 3));
      int rb = wn + i * 16 + rl;
      bfv[i] = *(const bf16x8*)(Bs + rb * 32 + ((q ^ (rb & 3)) << 3));
    }
#pragma unroll
    for (int i = 0; i < 4; ++i)
#pragma unroll
      for (int j = 0; j < 4; ++j)
        acc[i][j] = MFMA_BF16(af[i], bfv[j], acc[i][j]);
  }

#pragma unroll
  for (int i = 0; i < 4; ++i)
#pragma unroll
    for (int j = 0; j < 4; ++j)
#pragma unroll
      for (int r = 0; r < 4; ++r) {
        int gm = m_base + wm + i * 16 + q * 4 + r;
        int gn = n_base + wn + j * 16 + rl;
        int orow = ((gm & 511) << 6) | (gm >> 9);
        outp[(size_t)orow * 1024 + gn] = f2b(acc[i][j][r]);
      }
}

// ---------------- XCD-local fused 2-layer persistent scan ----------------
__global__ __launch_bounds__(64, 1) void scan_kernel(
    const u16* __restrict__ whh0, const u16* __restrict__ whh1,
    const u16* __restrict__ wih1, const u16* __restrict__ pre0,
    const float* __restrict__ bv0, const float* __restrict__ bv1,
    u32* __restrict__ h0ring, u32* __restrict__ h1ring,
    u32* flags, int* cnt, u32* __restrict__ hlast) {
  __shared__ u16 Whh[32 * 1024];  // 64KB

  const int lane = threadIdx.x;
  u32 xcc;
  asm volatile("s_getreg_b32 %0, hwreg(HW_REG_XCC_ID, 0, 32)" : "=s"(xcc));
  const int g = (int)(xcc & 7u);
  int r0 = 0;
  if (lane == 0) r0 = atomicAdd(cnt + g, 1);
  const int rr = __shfl(r0, 0);
  if (rr >= 64) return;  // cannot happen at exact capacity
  const bool isL0 = rr < 32;
  const int s = rr & 31;
  const int c0 = s * 32;
  const int rl = lane & 15;
  const int q = lane >> 4;

  // stage W_hh slice (rows c0..c0+31), 16B-chunk XOR swizzle by (n&7)
  {
    const u16* wsrc = isL0 ? whh0 : whh1;
#pragma unroll 4
    for (int i = 0; i < 64; ++i) {
      int idx = i * 64 + lane;
      int n = idx >> 7;
      int c = idx & 127;
      bf16x8 v = *(const bf16x8*)(wsrc + (size_t)(c0 + n) * 1024 + c * 8);
      *(bf16x8*)(Whh + n * 1024 + ((c ^ (n & 7)) << 3)) = v;
    }
  }
  __syncthreads();

  const float* bv = isL0 ? bv0 : bv1;
  const float bias0 = bv[c0 + rl];
  const float bias1 = bv[c0 + 16 + rl];

  u32* fown = flags + g * 64 + rr;
  const u32* fpoll = flags + g * 64 + lane;
  // L0 at t: L0 sibs >= t, L1 >= t-15 (h0 ring depth 16).
  // L1 at t: L0 >= t+1 (h0(t) ready), L1 sibs >= t.
  const int tgtd = isL0 ? (lane < 32 ? 0 : -15) : (lane < 32 ? 1 : 0);

  u32* h0g = h0ring + g * 131072;  // [16 slots][8 rows][1024] u32
  u32* h1g = h1ring + g * 131072;
  const int gr = g * 8;
  const int arow = (rl & 7) * 1024 + q * 8;  // M=8: rows 8..15 duplicate 0..7
  const int wrow = (q * 4) * 1024 + c0 + rl; // valid for q<2 only

  const u16* w0p = Whh + rl * 1024;
  const u16* w1p = Whh + (16 + rl) * 1024;
  const u16* wi0base = wih1 + (size_t)(c0 + rl) * 1024 + q * 8;
  const u16* wi1base = wi0base + 16 * 1024;

  for (int t = 0; t < 512; ++t) {
    // L0: pre0 prefetch (plain cached) before poll; poll's vmcnt(0) drains it
    u16 praw[8];
    if (isL0) {
      const u16* pt = pre0 + (size_t)t * 65536 +
                      ((q < 2) ? ((gr + q * 4) * 1024 + c0 + rl)
                               : (gr * 1024 + c0 + rl));  // clamp unused lanes
#pragma unroll
      for (int r = 0; r < 4; ++r) {
        praw[r] = pt[r * 1024];
        praw[4 + r] = pt[r * 1024 + 16];
      }
    }

    // ---- bounded flag poll: L1-invalidate each iteration, read local L2 ----
    {
      const int tgt = t + tgtd;
      for (int it = 0; it < 65536; ++it) {
        int fv;
        asm volatile("buffer_inv sc0\n\t"
                     "global_load_dword %0, %1, off sc0\n\t"
                     "s_waitcnt vmcnt(0)"
                     : "=v"(fv) : "v"(fpoll) : "memory");
        if (__all(fv >= tgt)) break;
        __builtin_amdgcn_s_sleep(1);
      }
      // final L1 invalidate so the data ladders below read fresh L2 lines
      asm volatile("buffer_inv sc0\n\t"
                   "s_waitcnt vmcnt(0)" ::: "memory");
      __builtin_amdgcn_sched_barrier(0);
    }

    f32x4 acc0 = {0.f, 0.f, 0.f, 0.f}, acc1 = {0.f, 0.f, 0.f, 0.f};

    if (isL0) {
      // ---- layer-0: h0(t-1) from slot (t+15)&15, 64 sc0 loads, 3-deep ladder
      const u32* ap = h0g + ((t + 15) & 15) * 8192 + arow;
      u32x4 st[3][4][2];
#define L0I(b, pb) do { \
      LD2L2(st[b][0][0], st[b][0][1], (pb), "0", "16"); \
      LD2L2(st[b][1][0], st[b][1][1], (pb), "128", "144"); \
      LD2L2(st[b][2][0], st[b][2][1], (pb), "256", "272"); \
      LD2L2(st[b][3][0], st[b][3][1], (pb), "384", "400"); } while (0)
#define L0C(ph, b) _Pragma("unroll") for (int j = 0; j < 4; ++j) { \
      int kt = (ph) * 4 + j; \
      bf16x8 ah = hi_frag(st[b][j][0], st[b][j][1]); \
      bf16x8 al = lo_frag(st[b][j][0], st[b][j][1]); \
      int cc = ((kt * 4 + q) ^ (rl & 7)) << 3; \
      bf16x8 w0 = *(const bf16x8*)(w0p + cc); \
      bf16x8 w1 = *(const bf16x8*)(w1p + cc); \
      acc0 = MFMA_BF16(ah, w0, acc0); acc0 = MFMA_BF16(al, w0, acc0); \
      acc1 = MFMA_BF16(ah, w1, acc1); acc1 = MFMA_BF16(al, w1, acc1); }
      L0I(0, ap); L0I(1, ap + 128); L0I(2, ap + 256);
      WAITVM(16); L0C(0, 0) L0I(0, ap + 384);
      WAITVM(16); L0C(1, 1) L0I(1, ap + 512);
      WAITVM(16); L0C(2, 2) L0I(2, ap + 640);
      WAITVM(16); L0C(3, 0) L0I(0, ap + 768);
      WAITVM(16); L0C(4, 1) L0I(1, ap + 896);
      WAITVM(16); L0C(5, 2)
      WAITVM(8);  L0C(6, 0)
      WAITVM(0);  L0C(7, 1)
#undef L0I
#undef L0C
    } else {
      // ---- layer-1: h0(t) slot t&15 + h1(t-1) slot (t+15)&15 + wih (cached)
      const u32* h0p = h0g + (t & 15) * 8192 + arow;
      const u32* h1p = h1g + ((t + 15) & 15) * 8192 + arow;
      u32x4 s0[2][4][2], s1[2][4][2], sw0[2][4], sw1[2][4];
#define L1I(b, hb0, hb1, wb0, wb1) do { \
      LD2L2(s0[b][0][0], s0[b][0][1], (hb0), "0", "16"); \
      LD2L2(s1[b][0][0], s1[b][0][1], (hb1), "0", "16"); \
      LD1CA(sw0[b][0], (wb0), "0"); LD1CA(sw1[b][0], (wb1), "0"); \
      LD2L2(s0[b][1][0], s0[b][1][1], (hb0), "128", "144"); \
      LD2L2(s1[b][1][0], s1[b][1][1], (hb1), "128", "144"); \
      LD1CA(sw0[b][1], (wb0), "64"); LD1CA(sw1[b][1], (wb1), "64"); \
      LD2L2(s0[b][2][0], s0[b][2][1], (hb0), "256", "272"); \
      LD2L2(s1[b][2][0], s1[b][2][1], (hb1), "256", "272"); \
      LD1CA(sw0[b][2], (wb0), "128"); LD1CA(sw1[b][2], (wb1), "128"); \
      LD2L2(s0[b][3][0], s0[b][3][1], (hb0), "384", "400"); \
      LD2L2(s1[b][3][0], s1[b][3][1], (hb1), "384", "400"); \
      LD1CA(sw0[b][3], (wb0), "192"); LD1CA(sw1[b][3], (wb1), "192"); } while (0)
#define L1C(ph, b) _Pragma("unroll") for (int j = 0; j < 4; ++j) { \
      int kt = (ph) * 4 + j; \
      bf16x8 a0h = hi_frag(s0[b][j][0], s0[b][j][1]); \
      bf16x8 a1h = hi_frag(s1[b][j][0], s1[b][j][1]); \
      bf16x8 a1l = lo_frag(s1[b][j][0], s1[b][j][1]); \
      int cc = ((kt * 4 + q) ^ (rl & 7)) << 3; \
      bf16x8 wh0 = *(const bf16x8*)(w0p + cc); \
      bf16x8 wh1 = *(const bf16x8*)(w1p + cc); \
      acc0 = MFMA_BF16(a1h, wh0, acc0); acc0 = MFMA_BF16(a1l, wh0, acc0); \
      acc0 = MFMA_BF16(a0h, __builtin_bit_cast(bf16x8, sw0[b][j]), acc0); \
      acc1 = MFMA_BF16(a1h, wh1, acc1); acc1 = MFMA_BF16(a1l, wh1, acc1); \
      acc1 = MFMA_BF16(a0h, __builtin_bit_cast(bf16x8, sw1[b][j]), acc1); }
      L1I(0, h0p, h1p, wi0base, wi1base);
      L1I(1, h0p + 128, h1p + 128, wi0base + 128, wi1base + 128);
      WAITVM(24); L1C(0, 0) L1I(0, h0p + 256, h1p + 256, wi0base + 256, wi1base + 256);
      WAITVM(24); L1C(1, 1) L1I(1, h0p + 384, h1p + 384, wi0base + 384, wi1base + 384);
      WAITVM(24); L1C(2, 0) L1I(0, h0p + 512, h1p + 512, wi0base + 512, wi1base + 512);
      WAITVM(24); L1C(3, 1) L1I(1, h0p + 640, h1p + 640, wi0base + 640, wi1base + 640);
      WAITVM(24); L1C(4, 0) L1I(0, h0p + 768, h1p + 768, wi0base + 768, wi1base + 768);
      WAITVM(24); L1C(5, 1) L1I(1, h0p + 896, h1p + 896, wi0base + 896, wi1base + 896);
      WAITVM(24); L1C(6, 0)
      WAITVM(0);  L1C(7, 1)
#undef L1I
#undef L1C
    }

    // ---- epilogue: h = relu(acc + (pre|0) + bias), pack hi|lo, sc0 stores
    if (q < 2) {
      u32 pk[8];
#pragma unroll
      for (int r = 0; r < 4; ++r) {
        float v0 = acc0[r] + bias0;
        float v1 = acc1[r] + bias1;
        if (isL0) { v0 += b2f(praw[r]); v1 += b2f(praw[4 + r]); }
        v0 = fmaxf(v0, 0.f);
        v1 = fmaxf(v1, 0.f);
        u16 h = f2b(v0);
        u16 l = f2b(v0 - b2f(h));
        pk[r] = (u32)h | ((u32)l << 16);
        u16 h2 = f2b(v1);
        u16 l2 = f2b(v1 - b2f(h2));
        pk[4 + r] = (u32)h2 | ((u32)l2 << 16);
      }
      u32* wb = (isL0 ? h0g : h1g) + (t & 15) * 8192 + wrow;
#pragma unroll
      for (int r = 0; r < 4; ++r) {
        STORE_L2(wb + r * 1024, pk[r]);
        STORE_L2(wb + r * 1024 + 16, pk[4 + r]);
      }
      if (!isL0 && t == 511) {  // export final h1 for the head (plain path)
        u32* hl = hlast + (gr + q * 4) * 1024 + c0 + rl;
#pragma unroll
        for (int r = 0; r < 4; ++r) {
          hl[r * 1024] = pk[r];
          hl[r * 1024 + 16] = pk[4 + r];
        }
      }
    }
    // drain h stores to local L2, then publish flag (sc0 store)
    WAITVM(0);
    if (lane == 0) STORE_L2(fown, (u32)(t + 1));
  }
}

// ---------------- head: logits = h1_last @ w_lin^T + b_lin ----------------
__global__ __launch_bounds__(64) void logits_kernel(const u32* __restrict__ hpk,  // packed [64][1024]
                                                    const u16* __restrict__ wl,   // [1008][1024]
                                                    const float* __restrict__ blin,
                                                    float* __restrict__ lg) {     // [64][1008]
  const int wgn = blockIdx.x;  // 0..62
  const int lane = threadIdx.x;
  const int rl = lane & 15;
  const int q = lane >> 4;
  f32x4 acc[4] = {};
  const u16* brow = wl + (size_t)(wgn * 16 + rl) * 1024 + q * 8;
  for (int kt = 0; kt < 32; ++kt) {
    bf16x8 bfv = *(const bf16x8*)(brow + kt * 32);
#pragma unroll
    for (int mi = 0; mi < 4; ++mi) {
      const u32* hp = hpk + (mi * 16 + rl) * 1024 + kt * 32 + q * 8;
      u32x4 d0 = *(const u32x4*)hp;
      u32x4 d1 = *(const u32x4*)(hp + 4);
      acc[mi] = MFMA_BF16(hi_frag(d0, d1), bfv, acc[mi]);
      acc[mi] = MFMA_BF16(lo_frag(d0, d1), bfv, acc[mi]);
    }
  }
  int col = wgn * 16 + rl;
  float bb = (col < 1000) ? blin[col] : 0.f;
#pragma unroll
  for (int mi = 0; mi < 4; ++mi)
#pragma unroll
    for (int r = 0; r < 4; ++r) {
      int row = mi * 16 + q * 4 + r;
      lg[row * 1008 + col] = acc[mi][r] + bb;
    }
}

__global__ __launch_bounds__(64) void lsm_kernel(const float* __restrict__ lg,
                                                 float* __restrict__ outp) {
  const int b = blockIdx.x;
  const int lane = threadIdx.x;
  float x[16];
  float m = -1e30f;
#pragma unroll
  for (int i = 0; i < 16; ++i) {
    int o = lane + i * 64;
    x[i] = (o < 1000) ? lg[b * 1008 + o] : -1e30f;
    m = fmaxf(m, x[i]);
  }
  for (int s = 32; s > 0; s >>= 1) m = fmaxf(m, __shfl_xor(m, s, 64));
  float sum = 0.f;
#pragma unroll
  for (int i = 0; i < 16; ++i) sum += expf(x[i] - m);
  for (int s = 32; s > 0; s >>= 1) sum += __shfl_xor(sum, s, 64);
  float lse = m + logf(sum);
#pragma unroll
  for (int i = 0; i < 16; ++i) {
    int o = lane + i * 64;
    if (o < 1000) outp[b * 1000 + o] = x[i] - lse;
  }
}

// ---------------- launch ----------------
extern "C" void kernel_launch(void* const* d_in, const int* in_sizes, int n_in,
                              void* d_out, int out_size, void* d_ws, size_t ws_size,
                              hipStream_t stream) {
  (void)in_sizes; (void)n_in; (void)out_size;
  const int B = 64, T = 512, I = 256, H = 1024, O = 1000;

  const float* x = (const float*)d_in[0];
  const float* w_ih0 = (const float*)d_in[1];
  const float* w_hh0 = (const float*)d_in[2];
  const float* b_ih0 = (const float*)d_in[3];
  const float* b_hh0 = (const float*)d_in[4];
  const float* w_ih1 = (const float*)d_in[5];
  const float* w_hh1 = (const float*)d_in[6];
  const float* b_ih1 = (const float*)d_in[7];
  const float* b_hh1 = (const float*)d_in[8];
  const float* w_lin = (const float*)d_in[9];
  const float* b_lin = (const float*)d_in[10];

  size_t off = 0;
  char* ws = (char*)d_ws;
  auto take = [&](size_t bytes) -> void* {
    void* p = ws + off;
    off += (bytes + 255) & ~(size_t)255;
    return p;
  };
  u16* pre = (u16*)take((size_t)T * B * H * 2);   // 64MB
  u16* xbf = (u16*)take((size_t)B * T * I * 2);   // 16MB
  u16* wih0b = (u16*)take((size_t)H * I * 2);
  u16* whh0b = (u16*)take((size_t)H * H * 2);
  u16* wih1b = (u16*)take((size_t)H * H * 2);
  u16* whh1b = (u16*)take((size_t)H * H * 2);
  u16* wlinb = (u16*)take((size_t)1008 * H * 2);
  float* bv0 = (float*)take((size_t)H * 4);
  float* bv1 = (float*)take((size_t)H * 4);
  u32* h0ring = (u32*)take((size_t)8 * 16 * 8 * H * 4);  // [8 grp][16 slot][8][1024]
  u32* h1ring = (u32*)take((size_t)8 * 16 * 8 * H * 4);
  u32* hlast = (u32*)take((size_t)B * H * 4);            // packed h1(T-1)
  u32* flags = (u32*)take((size_t)8 * 64 * 4);
  int* cnt = (int*)take((size_t)64 * 4);
  float* lgt = (float*)take((size_t)B * 1008 * 4);
  if (off > ws_size) return;

  // casts
  cast_kernel<<<(B * T * I / 4) / 256, 256, 0, stream>>>(x, xbf, B * T * I / 4);
  cast_kernel<<<(H * I / 4) / 256, 256, 0, stream>>>(w_ih0, wih0b, H * I / 4);
  cast_kernel<<<(H * H / 4) / 256, 256, 0, stream>>>(w_hh0, whh0b, H * H / 4);
  cast_kernel<<<(H * H / 4) / 256, 256, 0, stream>>>(w_ih1, wih1b, H * H / 4);
  cast_kernel<<<(H * H / 4) / 256, 256, 0, stream>>>(w_hh1, whh1b, H * H / 4);
  cast_kernel<<<(O * H / 4) / 256, 256, 0, stream>>>(w_lin, wlinb, O * H / 4);
  bias_kernel<<<4, 256, 0, stream>>>(b_ih0, b_hh0, bv0, H);
  bias_kernel<<<4, 256, 0, stream>>>(b_ih1, b_hh1, bv1, H);

  init_sync_kernel<<<256, 256, 0, stream>>>(h0ring, h1ring, flags, cnt);

  gemm_pre<<<dim3((B * T / 128) * (H / 128)), 256, 0, stream>>>(xbf, wih0b, pre, I);

  // exact-capacity persistent launch: 512 blocks x 64KB LDS = 2/CU everywhere
  scan_kernel<<<512, 64, 0, stream>>>(whh0b, whh1b, wih1b, pre, bv0, bv1,
                                      h0ring, h1ring, flags, cnt, hlast);

  logits_kernel<<<63, 64, 0, stream>>>(hlast, wlinb, b_lin, lgt);
  lsm_kernel<<<64, 64, 0, stream>>>(lgt, (float*)d_out);
}

// Round 10
// 7514.993 us; speedup vs baseline: 374.5301x; 374.5301x over previous
//
#include <hip/hip_runtime.h>

// SimpleRNN: 2-layer ReLU RNN, B=64 T=512 I=256 H=1024 O=1000, fp32 in/out.
// Round 10: r5 geometry + MALL (sc0sc1) fabric, but FLAG-FREE forward sync:
// each packed h word carries a 1-bit ring-phase tag (lo-plane LSB). Consumers
// load h and retry until all words match the expected epoch — the poll IS the
// data fetch (1 RT instead of 3 + detect). Overwrite safety via a full-group
// rendezvous every 8 steps (skew <= 8 < ring depth 16), off the critical path.

typedef float f32x4 __attribute__((ext_vector_type(4)));
typedef short bf16x8 __attribute__((ext_vector_type(8)));
typedef unsigned short u16;
typedef unsigned int u32;
typedef u32 u32x4 __attribute__((ext_vector_type(4)));

#define MFMA_BF16(a, b, c) __builtin_amdgcn_mfma_f32_16x16x32_bf16((a), (b), (c), 0, 0, 0)

#define GLDS16(g, l) __builtin_amdgcn_global_load_lds( \
    (const __attribute__((address_space(1))) unsigned int*)(g), \
    (__attribute__((address_space(3))) unsigned int*)(l), 16, 0, 0)

// two MALL-coherent 16B loads from one base + literal byte offsets
#define LD2SC(d0, d1, b_, O1, O2) asm volatile( \
    "global_load_dwordx4 %0, %2, off offset:" O1 " sc0 sc1\n\t" \
    "global_load_dwordx4 %1, %2, off offset:" O2 " sc0 sc1" \
    : "=&v"(d0), "=&v"(d1) : "v"(b_))
// one normal cached 16B load (read-only weights)
#define LD1CA(d, b_) asm volatile( \
    "global_load_dwordx4 %0, %1, off" : "=&v"(d) : "v"(b_))
// MALL write-through dword store
#define STORE_SC(p, v) asm volatile("global_store_dword %0, %1, off sc0 sc1" :: "v"(p), "v"(v) : "memory")
// literal-counted vmcnt wait, pinned against scheduler motion (rule #18)
#define WAITVM(n) do { __builtin_amdgcn_sched_barrier(0); \
    asm volatile("s_waitcnt vmcnt(" #n ")" ::: "memory"); \
    __builtin_amdgcn_sched_barrier(0); } while (0)

__device__ __forceinline__ u16 f2b(float f) {  // RNE f32 -> bf16 bits
  unsigned int u = __builtin_bit_cast(unsigned int, f);
  u = (u + 0x7fffu + ((u >> 16) & 1u)) >> 16;
  return (u16)u;
}
__device__ __forceinline__ float b2f(u16 b) {
  unsigned int u = ((unsigned int)b) << 16;
  return __builtin_bit_cast(float, u);
}

// packed u32 = hi-bf16 (low16) | lo-bf16 (high16); extract 8-elem bf16 frags
__device__ __forceinline__ bf16x8 hi_frag(u32x4 d0, u32x4 d1) {
  u32x4 r;
  r[0] = __builtin_amdgcn_perm(d0[1], d0[0], 0x05040100u);
  r[1] = __builtin_amdgcn_perm(d0[3], d0[2], 0x05040100u);
  r[2] = __builtin_amdgcn_perm(d1[1], d1[0], 0x05040100u);
  r[3] = __builtin_amdgcn_perm(d1[3], d1[2], 0x05040100u);
  return __builtin_bit_cast(bf16x8, r);
}
__device__ __forceinline__ bf16x8 lo_frag(u32x4 d0, u32x4 d1) {
  u32x4 r;
  r[0] = __builtin_amdgcn_perm(d0[1], d0[0], 0x07060302u);
  r[1] = __builtin_amdgcn_perm(d0[3], d0[2], 0x07060302u);
  r[2] = __builtin_amdgcn_perm(d1[1], d1[0], 0x07060302u);
  r[3] = __builtin_amdgcn_perm(d1[3], d1[2], 0x07060302u);
  return __builtin_bit_cast(bf16x8, r);
}

// ---------------- elementwise helpers ----------------
__global__ void cast_kernel(const float* __restrict__ s, u16* __restrict__ d, int n4) {
  int i = blockIdx.x * blockDim.x + threadIdx.x;
  if (i >= n4) return;
  float4 v = ((const float4*)s)[i];
  ushort4 o;
  o.x = f2b(v.x); o.y = f2b(v.y); o.z = f2b(v.z); o.w = f2b(v.w);
  ((ushort4*)d)[i] = o;
}

__global__ void bias_kernel(const float* __restrict__ a, const float* __restrict__ b,
                            float* __restrict__ o, int n) {
  int i = blockIdx.x * blockDim.x + threadIdx.x;
  if (i < n) o[i] = a[i] + b[i];
}

// zero ring slot 15 of both rings (h(-1)=0, phase bit 0) + rendezvous flags,
// through the MALL path so the scan's sc0sc1 loads see them (r4-proven).
__global__ void init_sync_kernel(u32* __restrict__ h0r, u32* __restrict__ h1r,
                                 u32* __restrict__ Fl) {
  int i = blockIdx.x * blockDim.x + threadIdx.x;  // 0..65535
  u32 z = 0;
  STORE_SC(h0r + 15 * 65536 + i, z);
  STORE_SC(h1r + 15 * 65536 + i, z);
  if (i < 256) STORE_SC(Fl + i, z);
}

// ---------------- input GEMM: pre = A @ Bw^T  (A:[M][K], Bw:[1024][K]) ----------------
// rows m=b*512+t -> out row t*64+b (time-major). Out: bf16 [32768][1024].
__global__ __launch_bounds__(256) void gemm_pre(const u16* __restrict__ A,
                                                const u16* __restrict__ Bw,
                                                u16* __restrict__ outp, int K) {
  __shared__ u16 As[128 * 32];
  __shared__ u16 Bs[128 * 32];
  const int tid = threadIdx.x;
  const int lane = tid & 63;
  const int w = tid >> 6;
  const int nt = blockIdx.x & 7;
  const int mt = blockIdx.x >> 3;
  const int m_base = mt * 128;
  const int n_base = nt * 128;

  const int srow = w * 32 + (lane >> 2);
  const int schunk = (lane & 3) ^ (srow & 3);
  const u16* Ag0 = A + (size_t)(m_base + srow) * K + schunk * 8;
  const u16* Ag1 = A + (size_t)(m_base + srow + 16) * K + schunk * 8;
  const u16* Bg0 = Bw + (size_t)(n_base + srow) * K + schunk * 8;
  const u16* Bg1 = Bw + (size_t)(n_base + srow + 16) * K + schunk * 8;
  u16* AsD0 = As + (w * 32) * 32;
  u16* AsD1 = As + (w * 32 + 16) * 32;
  u16* BsD0 = Bs + (w * 32) * 32;
  u16* BsD1 = Bs + (w * 32 + 16) * 32;

  const int wm = (w & 1) * 64;
  const int wn = (w >> 1) * 64;
  const int rl = lane & 15;
  const int q = lane >> 4;

  f32x4 acc[4][4] = {};

  for (int k0 = 0; k0 < K; k0 += 32) {
    __syncthreads();
    GLDS16(Ag0 + k0, AsD0);
    GLDS16(Ag1 + k0, AsD1);
    GLDS16(Bg0 + k0, BsD0);
    GLDS16(Bg1 + k0, BsD1);
    __syncthreads();
    bf16x8 af[4], bfv[4];
#pragma unroll
    for (int i = 0; i < 4; ++i) {
      int ra = wm + i * 16 + rl;
      af[i] = *(const bf16x8*)(As + ra * 32 + ((q ^ (ra & 3)) << 3));
      int rb = wn + i * 16 + rl;
      bfv[i] = *(const bf16x8*)(Bs + rb * 32 + ((q ^ (rb & 3)) << 3));
    }
#pragma unroll
    for (int i = 0; i < 4; ++i)
#pragma unroll
      for (int j = 0; j < 4; ++j)
        acc[i][j] = MFMA_BF16(af[i], bfv[j], acc[i][j]);
  }

#pragma unroll
  for (int i = 0; i < 4; ++i)
#pragma unroll
    for (int j = 0; j < 4; ++j)
#pragma unroll
      for (int r = 0; r < 4; ++r) {
        int gm = m_base + wm + i * 16 + q * 4 + r;
        int gn = n_base + wn + j * 16 + rl;
        int orow = ((gm & 511) << 6) | (gm >> 9);
        outp[(size_t)orow * 1024 + gn] = f2b(acc[i][j][r]);
      }
}

// ---------------- fused 2-layer persistent scan, phase-tagged MALL rings ----
// 256 blocks x 256 threads (4 waves). bid<128: L0 role; else L1.
// Role (g, s): group g = 16 batch rows, slice s = 32 output cols.
// Wave wid handles k-tiles [wid*8, wid*8+8); partials combined in LDS; wave 0
// does reduce + epilogue + 8-step rendezvous. Rings: 16 slots, phase =
// ((t+16)>>4)&1 embedded in bit16 of every packed word.
__global__ __launch_bounds__(256, 2) void fused_scan(
    const u16* __restrict__ whh0, const u16* __restrict__ whh1,
    const u16* __restrict__ wih1, const u16* __restrict__ pre0,
    const float* __restrict__ bv0, const float* __restrict__ bv1,
    u32* h0ring, u32* h1ring, u32* Fl, u32* __restrict__ hlast) {
  __shared__ u16 Whh[32 * 1024];    // 64KB
  __shared__ float comb[4][64][8];  // 8KB

  const int bid = blockIdx.x;
  const bool isL0 = bid < 128;
  const int rb = isL0 ? bid : (bid - 128);
  const int g = rb >> 5;
  const int s = rb & 31;
  const int b0 = g * 16;
  const int c0 = s * 32;
  const int tid = threadIdx.x;
  const int lane = tid & 63;
  const int wid = tid >> 6;
  const int rl = lane & 15;
  const int q = lane >> 4;
  const int ktb = wid * 8;

  // stage W_hh slice (rows c0..c0+31), 16B-chunk XOR swizzle by (n&7)
  {
    const u16* wsrc = isL0 ? whh0 : whh1;
#pragma unroll
    for (int i = 0; i < 16; ++i) {
      int idx = i * 256 + tid;
      int n = idx >> 7;
      int c = idx & 127;
      bf16x8 v = *(const bf16x8*)(wsrc + (size_t)(c0 + n) * 1024 + c * 8);
      *(bf16x8*)(Whh + n * 1024 + ((c ^ (n & 7)) << 3)) = v;
    }
  }
  __syncthreads();

  const float* bv = isL0 ? bv0 : bv1;
  const float bias0 = bv[c0 + rl];
  const float bias1 = bv[c0 + 16 + rl];

  u32* fl_own = Fl + g * 64 + (isL0 ? s : 32 + s);
  const u32* fpoll = Fl + g * 64 + lane;

  const int hrow_off = (b0 + rl) * 1024 + q * 8;
  const int wrow_off = (b0 + q * 4) * 1024 + c0 + rl;
  u32* h0g = h0ring;  // [16][64][1024] u32
  u32* h1g = h1ring;

  const u16* wi0base = wih1 + (size_t)(c0 + rl) * 1024 + q * 8;
  const u16* wi1base = wi0base + 16 * 1024;
  const u16* w0p = Whh + rl * 1024;
  const u16* w1p = Whh + (16 + rl) * 1024;

  for (int t = 0; t < 512; ++t) {
    const u32 ph_prev = (u32)((t + 15) >> 4) & 1u;  // phase of h(t-1)
    const u32 ph_cur = (u32)((t + 16) >> 4) & 1u;   // phase of h(t)

    f32x4 acc0 = {0.f, 0.f, 0.f, 0.f}, acc1 = {0.f, 0.f, 0.f, 0.f};
    u16 praw[8];

    if (isL0) {
      // wave0 prefetches pre0 (plain loads; drained by the retry WAITVM(0))
      if (wid == 0) {
        const u16* pt = pre0 + (size_t)t * 65536 + wrow_off;
#pragma unroll
        for (int r = 0; r < 4; ++r) {
          praw[r] = pt[r * 1024];
          praw[4 + r] = pt[r * 1024 + 16];
        }
      }
      // ---- load h0(t-1) with phase-validated retry ----
      const u32* ap = h0g + ((t + 15) & 15) * 65536 + hrow_off;
      u32x4 st[8][2];
#pragma unroll
      for (int j = 0; j < 8; ++j) LD2SC(st[j][0], st[j][1], ap + (ktb + j) * 32, "0", "16");
      for (int tries = 0; tries < 65536; ++tries) {
        WAITVM(0);
        u32 aa = 0xFFFFFFFFu, oo = 0u;
#pragma unroll
        for (int j = 0; j < 8; ++j)
#pragma unroll
          for (int i2 = 0; i2 < 2; ++i2)
#pragma unroll
            for (int k2 = 0; k2 < 4; ++k2) { u32 w = st[j][i2][k2]; aa &= w; oo |= w; }
        bool ok = ph_prev ? (((aa >> 16) & 1u) != 0u) : (((oo >> 16) & 1u) == 0u);
        if (__all(ok)) break;
#pragma unroll
        for (int j = 0; j < 8; ++j) LD2SC(st[j][0], st[j][1], ap + (ktb + j) * 32, "0", "16");
      }
#pragma unroll
      for (int j = 0; j < 8; ++j) {
        int kt = ktb + j;
        bf16x8 ah = hi_frag(st[j][0], st[j][1]);
        bf16x8 al = lo_frag(st[j][0], st[j][1]);
        int cc = ((kt * 4 + q) ^ (rl & 7)) << 3;
        bf16x8 w0 = *(const bf16x8*)(w0p + cc);
        bf16x8 w1 = *(const bf16x8*)(w1p + cc);
        acc0 = MFMA_BF16(ah, w0, acc0); acc0 = MFMA_BF16(al, w0, acc0);
        acc1 = MFMA_BF16(ah, w1, acc1); acc1 = MFMA_BF16(al, w1, acc1);
      }
    } else {
      // ---- load h0(t) [phase ph_cur] + h1(t-1) [phase ph_prev], retry ----
      const u32* h0p = h0g + (t & 15) * 65536 + hrow_off;
      const u32* h1p = h1g + ((t + 15) & 15) * 65536 + hrow_off;
      u32x4 s0[8][2], s1[8][2];
#pragma unroll
      for (int j = 0; j < 8; ++j) {
        LD2SC(s0[j][0], s0[j][1], h0p + (ktb + j) * 32, "0", "16");
        LD2SC(s1[j][0], s1[j][1], h1p + (ktb + j) * 32, "0", "16");
      }
      for (int tries = 0; tries < 65536; ++tries) {
        WAITVM(0);
        u32 aa0 = 0xFFFFFFFFu, oo0 = 0u, aa1 = 0xFFFFFFFFu, oo1 = 0u;
#pragma unroll
        for (int j = 0; j < 8; ++j)
#pragma unroll
          for (int i2 = 0; i2 < 2; ++i2)
#pragma unroll
            for (int k2 = 0; k2 < 4; ++k2) {
              u32 w0 = s0[j][i2][k2]; aa0 &= w0; oo0 |= w0;
              u32 w1 = s1[j][i2][k2]; aa1 &= w1; oo1 |= w1;
            }
        bool ok0 = ph_cur ? (((aa0 >> 16) & 1u) != 0u) : (((oo0 >> 16) & 1u) == 0u);
        bool ok1 = ph_prev ? (((aa1 >> 16) & 1u) != 0u) : (((oo1 >> 16) & 1u) == 0u);
        if (__all(ok0 && ok1)) break;
#pragma unroll
        for (int j = 0; j < 8; ++j) {
          LD2SC(s0[j][0], s0[j][1], h0p + (ktb + j) * 32, "0", "16");
          LD2SC(s1[j][0], s1[j][1], h1p + (ktb + j) * 32, "0", "16");
        }
      }
      // w_ih in two cached chunks (L2-hot), compute interleaved
      u32x4 wa0[4], wa1[4];
#pragma unroll
      for (int j = 0; j < 4; ++j) {
        LD1CA(wa0[j], (const u32*)(wi0base + (ktb + j) * 32));
        LD1CA(wa1[j], (const u32*)(wi1base + (ktb + j) * 32));
      }
      WAITVM(0);
#pragma unroll
      for (int j = 0; j < 4; ++j) {
        int kt = ktb + j;
        bf16x8 a0h = hi_frag(s0[j][0], s0[j][1]);
        bf16x8 a1h = hi_frag(s1[j][0], s1[j][1]);
        bf16x8 a1l = lo_frag(s1[j][0], s1[j][1]);
        int cc = ((kt * 4 + q) ^ (rl & 7)) << 3;
        bf16x8 wh0 = *(const bf16x8*)(w0p + cc);
        bf16x8 wh1 = *(const bf16x8*)(w1p + cc);
        acc0 = MFMA_BF16(a1h, wh0, acc0); acc0 = MFMA_BF16(a1l, wh0, acc0);
        acc0 = MFMA_BF16(a0h, __builtin_bit_cast(bf16x8, wa0[j]), acc0);
        acc1 = MFMA_BF16(a1h, wh1, acc1); acc1 = MFMA_BF16(a1l, wh1, acc1);
        acc1 = MFMA_BF16(a0h, __builtin_bit_cast(bf16x8, wa1[j]), acc1);
      }
      u32x4 wb0[4], wb1[4];
#pragma unroll
      for (int j = 0; j < 4; ++j) {
        LD1CA(wb0[j], (const u32*)(wi0base + (ktb + 4 + j) * 32));
        LD1CA(wb1[j], (const u32*)(wi1base + (ktb + 4 + j) * 32));
      }
      WAITVM(0);
#pragma unroll
      for (int j = 0; j < 4; ++j) {
        int kt = ktb + 4 + j;
        bf16x8 a0h = hi_frag(s0[4 + j][0], s0[4 + j][1]);
        bf16x8 a1h = hi_frag(s1[4 + j][0], s1[4 + j][1]);
        bf16x8 a1l = lo_frag(s1[4 + j][0], s1[4 + j][1]);
        int cc = ((kt * 4 + q) ^ (rl & 7)) << 3;
        bf16x8 wh0 = *(const bf16x8*)(w0p + cc);
        bf16x8 wh1 = *(const bf16x8*)(w1p + cc);
        acc0 = MFMA_BF16(a1h, wh0, acc0); acc0 = MFMA_BF16(a1l, wh0, acc0);
        acc0 = MFMA_BF16(a0h, __builtin_bit_cast(bf16x8, wb0[j]), acc0);
        acc1 = MFMA_BF16(a1h, wh1, acc1); acc1 = MFMA_BF16(a1l, wh1, acc1);
        acc1 = MFMA_BF16(a0h, __builtin_bit_cast(bf16x8, wb1[j]), acc1);
      }
    }

    // ---- combine partials across waves ----
    *(f32x4*)&comb[wid][lane][0] = acc0;
    *(f32x4*)&comb[wid][lane][4] = acc1;
    __syncthreads();  // (A)

    if (wid == 0) {
      f32x4 A0 = acc0, A1 = acc1;
#pragma unroll
      for (int w = 1; w < 4; ++w) {
        A0 += *(const f32x4*)&comb[w][lane][0];
        A1 += *(const f32x4*)&comb[w][lane][4];
      }
      u32* wb = (isL0 ? h0g : h1g) + (t & 15) * 65536 + wrow_off;
      u32 pk[8];
#pragma unroll
      for (int r = 0; r < 4; ++r) {
        float v0 = A0[r] + bias0;
        float v1 = A1[r] + bias1;
        if (isL0) { v0 += b2f(praw[r]); v1 += b2f(praw[4 + r]); }
        v0 = fmaxf(v0, 0.f);
        v1 = fmaxf(v1, 0.f);
        u16 h = f2b(v0);
        u16 l = (u16)((f2b(v0 - b2f(h)) & 0xFFFEu) | ph_cur);
        pk[r] = (u32)h | ((u32)l << 16);
        STORE_SC(wb + r * 1024, pk[r]);
        u16 h2 = f2b(v1);
        u16 l2 = (u16)((f2b(v1 - b2f(h2)) & 0xFFFEu) | ph_cur);
        pk[4 + r] = (u32)h2 | ((u32)l2 << 16);
        STORE_SC(wb + r * 1024 + 16, pk[4 + r]);
      }
      if (!isL0 && t == 511) {  // export final h1 (plain path) for the head
        u32* hl = hlast + wrow_off;
#pragma unroll
        for (int r = 0; r < 4; ++r) {
          hl[r * 1024] = pk[r];
          hl[r * 1024 + 16] = pk[4 + r];
        }
      }
      // ---- rendezvous every 8 steps (overwrite safety; off critical path)
      if ((t & 7) == 7) {
        if (lane == 0) STORE_SC(fl_own, (u32)(t + 1));
        for (int it = 0; it < (1 << 20); ++it) {
          int fv;
          asm volatile("global_load_dword %0, %1, off sc0 sc1\n\t"
                       "s_waitcnt vmcnt(0)"
                       : "=v"(fv) : "v"(fpoll) : "memory");
          if (__all(fv >= t + 1)) break;
          __builtin_amdgcn_s_sleep(2);
        }
        __builtin_amdgcn_sched_barrier(0);
      }
    }
    __syncthreads();  // (B) protects comb + gates all waves behind epilogue
  }
}

// ---------------- head: logits = h1_last @ w_lin^T + b_lin ----------------
__global__ __launch_bounds__(64) void logits_kernel(const u32* __restrict__ hpk,  // packed [64][1024]
                                                    const u16* __restrict__ wl,   // [1008][1024]
                                                    const float* __restrict__ blin,
                                                    float* __restrict__ lg) {     // [64][1008]
  const int wgn = blockIdx.x;  // 0..62
  const int lane = threadIdx.x;
  const int rl = lane & 15;
  const int q = lane >> 4;
  f32x4 acc[4] = {};
  const u16* brow = wl + (size_t)(wgn * 16 + rl) * 1024 + q * 8;
  for (int kt = 0; kt < 32; ++kt) {
    bf16x8 bfv = *(const bf16x8*)(brow + kt * 32);
#pragma unroll
    for (int mi = 0; mi < 4; ++mi) {
      const u32* hp = hpk + (mi * 16 + rl) * 1024 + kt * 32 + q * 8;
      u32x4 d0 = *(const u32x4*)hp;
      u32x4 d1 = *(const u32x4*)(hp + 4);
      acc[mi] = MFMA_BF16(hi_frag(d0, d1), bfv, acc[mi]);
      acc[mi] = MFMA_BF16(lo_frag(d0, d1), bfv, acc[mi]);
    }
  }
  int col = wgn * 16 + rl;
  float bb = (col < 1000) ? blin[col] : 0.f;
#pragma unroll
  for (int mi = 0; mi < 4; ++mi)
#pragma unroll
    for (int r = 0; r < 4; ++r) {
      int row = mi * 16 + q * 4 + r;
      lg[row * 1008 + col] = acc[mi][r] + bb;
    }
}

__global__ __launch_bounds__(64) void lsm_kernel(const float* __restrict__ lg,
                                                 float* __restrict__ outp) {
  const int b = blockIdx.x;
  const int lane = threadIdx.x;
  float x[16];
  float m = -1e30f;
#pragma unroll
  for (int i = 0; i < 16; ++i) {
    int o = lane + i * 64;
    x[i] = (o < 1000) ? lg[b * 1008 + o] : -1e30f;
    m = fmaxf(m, x[i]);
  }
  for (int s = 32; s > 0; s >>= 1) m = fmaxf(m, __shfl_xor(m, s, 64));
  float sum = 0.f;
#pragma unroll
  for (int i = 0; i < 16; ++i) sum += expf(x[i] - m);
  for (int s = 32; s > 0; s >>= 1) sum += __shfl_xor(sum, s, 64);
  float lse = m + logf(sum);
#pragma unroll
  for (int i = 0; i < 16; ++i) {
    int o = lane + i * 64;
    if (o < 1000) outp[b * 1000 + o] = x[i] - lse;
  }
}

// ---------------- launch ----------------
extern "C" void kernel_launch(void* const* d_in, const int* in_sizes, int n_in,
                              void* d_out, int out_size, void* d_ws, size_t ws_size,
                              hipStream_t stream) {
  (void)in_sizes; (void)n_in; (void)out_size;
  const int B = 64, T = 512, I = 256, H = 1024, O = 1000;

  const float* x = (const float*)d_in[0];
  const float* w_ih0 = (const float*)d_in[1];
  const float* w_hh0 = (const float*)d_in[2];
  const float* b_ih0 = (const float*)d_in[3];
  const float* b_hh0 = (const float*)d_in[4];
  const float* w_ih1 = (const float*)d_in[5];
  const float* w_hh1 = (const float*)d_in[6];
  const float* b_ih1 = (const float*)d_in[7];
  const float* b_hh1 = (const float*)d_in[8];
  const float* w_lin = (const float*)d_in[9];
  const float* b_lin = (const float*)d_in[10];

  size_t off = 0;
  char* ws = (char*)d_ws;
  auto take = [&](size_t bytes) -> void* {
    void* p = ws + off;
    off += (bytes + 255) & ~(size_t)255;
    return p;
  };
  u16* pre = (u16*)take((size_t)T * B * H * 2);   // 64MB
  u16* xbf = (u16*)take((size_t)B * T * I * 2);   // 16MB
  u16* wih0b = (u16*)take((size_t)H * I * 2);
  u16* whh0b = (u16*)take((size_t)H * H * 2);
  u16* wih1b = (u16*)take((size_t)H * H * 2);
  u16* whh1b = (u16*)take((size_t)H * H * 2);
  u16* wlinb = (u16*)take((size_t)1008 * H * 2);
  float* bv0 = (float*)take((size_t)H * 4);
  float* bv1 = (float*)take((size_t)H * 4);
  u32* h0ring = (u32*)take((size_t)16 * B * H * 4);  // 4MB, phase-tagged
  u32* h1ring = (u32*)take((size_t)16 * B * H * 4);
  u32* hlast = (u32*)take((size_t)B * H * 4);
  u32* Fl = (u32*)take((size_t)4 * 64 * 4);
  float* lgt = (float*)take((size_t)B * 1008 * 4);
  if (off > ws_size) return;

  // casts
  cast_kernel<<<(B * T * I / 4) / 256, 256, 0, stream>>>(x, xbf, B * T * I / 4);
  cast_kernel<<<(H * I / 4) / 256, 256, 0, stream>>>(w_ih0, wih0b, H * I / 4);
  cast_kernel<<<(H * H / 4) / 256, 256, 0, stream>>>(w_hh0, whh0b, H * H / 4);
  cast_kernel<<<(H * H / 4) / 256, 256, 0, stream>>>(w_ih1, wih1b, H * H / 4);
  cast_kernel<<<(H * H / 4) / 256, 256, 0, stream>>>(w_hh1, whh1b, H * H / 4);
  cast_kernel<<<(O * H / 4) / 256, 256, 0, stream>>>(w_lin, wlinb, O * H / 4);
  bias_kernel<<<4, 256, 0, stream>>>(b_ih0, b_hh0, bv0, H);
  bias_kernel<<<4, 256, 0, stream>>>(b_ih1, b_hh1, bv1, H);

  init_sync_kernel<<<256, 256, 0, stream>>>(h0ring, h1ring, Fl);

  gemm_pre<<<dim3((B * T / 128) * (H / 128)), 256, 0, stream>>>(xbf, wih0b, pre, I);

  // persistent fused scan: 256 blocks x 4 waves, 72KB LDS -> 2 blocks/CU,
  // all co-resident.
  fused_scan<<<256, 256, 0, stream>>>(whh0b, whh1b, wih1b, pre, bv0, bv1,
                                      h0ring, h1ring, Fl, hlast);

  logits_kernel<<<63, 64, 0, stream>>>(hlast, wlinb, b_lin, lgt);
  lsm_kernel<<<64, 64, 0, stream>>>(lgt, (float*)d_out);
}